// Round 7
// baseline (16517.206 us; speedup 1.0000x reference)
//
#include <hip/hip_runtime.h>

// ODE_Vanilla scan: B=128, T=256, I=256, H=1024, C=10, fp32 throughout.
//   phase1: v = a*h - relu(h@Wh + XW[t])   (XW = X@Wx + b precomputed)
//   phase2: u = v@Wh^T; grad = a*v - (phi>0)*u; h -= LR*grad; out[b,t,:]=h@fc_w+fc_b
// R9: R7 structure (direct-global rows, value-split reduce, FC-in-phase2,
// multi-launch) with 16-row x 16-col blocks: 512 blocks = exactly 2/CU,
// 512 threads = c4(4) x kk(128). Halves W-read redundancy (16->8 rt groups
// sharing Wh: 64->32 MB/phase). acc[16]=64 VGPR, load-and-consume h rows
// (no preload array -> no R6-style spills). 4-stage all-float4 value-split
// butterfly (15 shfl4). Epilogue operands prefetched at kernel start.
// NEVER exceed co-resident grid (R8: 1040 blocks = +1 ms).

constexpr int Bsz = 128, Tn = 256, In = 256, Hn = 1024, Cn = 10;
constexpr float LR = 0.001f;

__global__ __launch_bounds__(256) void k_transpose(const float* __restrict__ W,
                                                   float* __restrict__ WT) {
  __shared__ float tile[32][33];
  const int bx = blockIdx.x * 32, by = blockIdx.y * 32;
  const int tx = threadIdx.x & 31, ty = threadIdx.x >> 5;
#pragma unroll
  for (int dy = 0; dy < 32; dy += 8)
    tile[ty + dy][tx] = W[(size_t)(by + ty + dy) * Hn + bx + tx];
  __syncthreads();
#pragma unroll
  for (int dy = 0; dy < 32; dy += 8)
    WT[(size_t)(bx + ty + dy) * Hn + by + tx] = tile[tx][ty + dy];
}

__global__ __launch_bounds__(256) void k_init(float* __restrict__ out,
                                              const float* __restrict__ fc_b,
                                              float* __restrict__ h_cur,
                                              const float* __restrict__ hidden) {
  const int i = blockIdx.x * blockDim.x + threadIdx.x;
  if (i < Bsz * Tn * Cn) out[i] = fc_b[i % Cn];
  if (i < Bsz * Hn) h_cur[i] = hidden[i];
}

__device__ __forceinline__ void fma4(float4& a, float s, const float4& w) {
  a.x = fmaf(s, w.x, a.x);
  a.y = fmaf(s, w.y, a.y);
  a.z = fmaf(s, w.z, a.z);
  a.w = fmaf(s, w.w, a.w);
}

__device__ __forceinline__ float4 shfl4(float4 v, int m) {
  v.x = __shfl_xor(v.x, m, 64);
  v.y = __shfl_xor(v.y, m, 64);
  v.z = __shfl_xor(v.z, m, 64);
  v.w = __shfl_xor(v.w, m, 64);
  return v;
}

__device__ __forceinline__ float4 add4(float4 a, float4 b) {
  return make_float4(a.x + b.x, a.y + b.y, a.z + b.z, a.w + b.w);
}

// XW[t][b][n] = sum_k X[b][t][k]*Wx[k][n] + bias[n].
__global__ __launch_bounds__(256) void k_xw(const float* __restrict__ X,
                                            const float* __restrict__ Wx,
                                            const float* __restrict__ bias,
                                            float* __restrict__ xw) {
  const int nt = blockIdx.x & 15, mt = blockIdx.x >> 4;
  const int t = mt >> 1, b0 = (mt & 1) * 64;
  const int cl = threadIdx.x & 15, rg = threadIdx.x >> 4;
  const int col = nt * 64 + cl * 4;
  const int row = b0 + rg * 4;
  float4 acc0 = {0, 0, 0, 0}, acc1 = {0, 0, 0, 0}, acc2 = {0, 0, 0, 0},
         acc3 = {0, 0, 0, 0};
  const size_t xstride = (size_t)Tn * In;
  const float* xp = X + ((size_t)row * Tn + t) * In;
  const float* wp = Wx + col;
#pragma unroll 2
  for (int k = 0; k < In; k += 4) {
    const float4 x0 = *(const float4*)(xp + k);
    const float4 x1 = *(const float4*)(xp + xstride + k);
    const float4 x2 = *(const float4*)(xp + 2 * xstride + k);
    const float4 x3 = *(const float4*)(xp + 3 * xstride + k);
    const float4 w0 = *(const float4*)(wp + (size_t)k * Hn);
    const float4 w1 = *(const float4*)(wp + (size_t)(k + 1) * Hn);
    const float4 w2 = *(const float4*)(wp + (size_t)(k + 2) * Hn);
    const float4 w3 = *(const float4*)(wp + (size_t)(k + 3) * Hn);
    fma4(acc0, x0.x, w0); fma4(acc0, x0.y, w1); fma4(acc0, x0.z, w2); fma4(acc0, x0.w, w3);
    fma4(acc1, x1.x, w0); fma4(acc1, x1.y, w1); fma4(acc1, x1.z, w2); fma4(acc1, x1.w, w3);
    fma4(acc2, x2.x, w0); fma4(acc2, x2.y, w1); fma4(acc2, x2.z, w2); fma4(acc2, x2.w, w3);
    fma4(acc3, x3.x, w0); fma4(acc3, x3.y, w1); fma4(acc3, x3.z, w2); fma4(acc3, x3.w, w3);
  }
  const float4 b4 = *(const float4*)(bias + col);
  float4 o[4] = {acc0, acc1, acc2, acc3};
#pragma unroll
  for (int i = 0; i < 4; i++) {
    float4 v = o[i];
    v.x += b4.x; v.y += b4.y; v.z += b4.z; v.w += b4.w;
    *(float4*)(xw + ((size_t)t * Bsz + row + i) * Hn + col) = v;
  }
}

// 16-rows x 16-cols x K=1024 panel GEMM; thread = c4(4) x kk(128). Rows read
// straight from global (c4-lanes broadcast-merge); W float4 loaded once per
// 16 rows. k = 4*kk + 512*q, q in {0,1}.
__device__ __forceinline__ void gemm16g(const float* __restrict__ rows,
                                        const float* __restrict__ W, int kk,
                                        int col, float4 acc[16]) {
#pragma unroll
  for (int q = 0; q < 2; q++) {
    const int k = 4 * kk + 512 * q;
    const float* Wp = W + (size_t)k * Hn + col;
    const float4 w0 = *(const float4*)(Wp);
    const float4 w1 = *(const float4*)(Wp + Hn);
    const float4 w2 = *(const float4*)(Wp + 2 * Hn);
    const float4 w3 = *(const float4*)(Wp + 3 * Hn);
#pragma unroll
    for (int r = 0; r < 16; r++) {
      const float4 h4 = *(const float4*)(rows + (size_t)r * Hn + k);
      fma4(acc[r], h4.x, w0);
      fma4(acc[r], h4.y, w1);
      fma4(acc[r], h4.z, w2);
      fma4(acc[r], h4.w, w3);
    }
  }
}

// 4-stage all-float4 value-splitting butterfly over ksw = lane bits 2..5
// (15 shfl4 total). Lane ends owning row r_own = 8u1+4u2+2u3+u4, cols
// 4*c4..+3; stores float4 to part[wv] (stride-20 rows to spread banks).
__device__ __forceinline__ void reduce_vs16(float4 acc[16], int c4, int ksw,
                                            int wv, float (*part)[16][20]) {
  const bool u1 = ksw & 1;
#pragma unroll
  for (int i = 0; i < 8; i++) {
    const float4 snd = u1 ? acc[i] : acc[i + 8];
    const float4 kp = u1 ? acc[i + 8] : acc[i];
    acc[i] = add4(kp, shfl4(snd, 4));
  }
  const bool u2 = ksw & 2;
#pragma unroll
  for (int i = 0; i < 4; i++) {
    const float4 snd = u2 ? acc[i] : acc[i + 4];
    const float4 kp = u2 ? acc[i + 4] : acc[i];
    acc[i] = add4(kp, shfl4(snd, 8));
  }
  const bool u3 = ksw & 4;
#pragma unroll
  for (int i = 0; i < 2; i++) {
    const float4 snd = u3 ? acc[i] : acc[i + 2];
    const float4 kp = u3 ? acc[i + 2] : acc[i];
    acc[i] = add4(kp, shfl4(snd, 16));
  }
  const bool u4 = ksw & 8;
  {
    const float4 snd = u4 ? acc[0] : acc[1];
    const float4 kp = u4 ? acc[1] : acc[0];
    acc[0] = add4(kp, shfl4(snd, 32));
  }
  const int r_own = (u1 ? 8 : 0) | (u2 ? 4 : 0) | (u3 ? 2 : 0) | (u4 ? 1 : 0);
  *(float4*)&part[wv][r_own][4 * c4] = acc[0];
}

// grid 512 = rt(8, 16 rows) x ct(64, 16 cols); block 512 = c4(4) x kk(128).
template <int PRE>
__global__ __launch_bounds__(512, 4) void k_phase1(
    const float* __restrict__ h, const float* __restrict__ X,
    const float* __restrict__ Wh, const float* __restrict__ Wx,
    const float* __restrict__ bias, const float* __restrict__ alpha,
    const float* __restrict__ xw, float* __restrict__ v_out, int t) {
  __shared__ float part[8][16][20];  // 10.2 KB
  const int ct = blockIdx.x & 63, rt = blockIdx.x >> 6;
  const int c0 = ct * 16, r0 = rt * 16;
  const int tid = threadIdx.x;
  const int c4 = tid & 3, kk = tid >> 2;
  const int col = c0 + 4 * c4;
  const int wv = tid >> 6, ksw = (tid >> 2) & 15;
  const float* hbase = h + (size_t)r0 * Hn;

  // prefetch epilogue operands (used after the reduce)
  float a1 = 0.f, hv = 0.f;
  if (tid < 256) {
    const int r = tid >> 4, c = tid & 15;
    a1 = PRE ? xw[((size_t)t * Bsz + r0 + r) * Hn + c0 + c] : bias[c0 + c];
    hv = hbase[(size_t)r * Hn + c0 + c];
  }

  float4 acc[16];
#pragma unroll
  for (int r = 0; r < 16; r++) acc[r] = {0.f, 0.f, 0.f, 0.f};
  gemm16g(hbase, Wh, kk, col, acc);
  if (!PRE) {  // x@Wx inline: thread kk owns Wx row-pair {2kk, 2kk+1}
    const int kx = 2 * kk;
    const float* Wp = Wx + (size_t)kx * Hn + col;
    const float4 wa = *(const float4*)(Wp);
    const float4 wb = *(const float4*)(Wp + Hn);
#pragma unroll
    for (int r = 0; r < 16; r++) {
      const float2 x2 =
          *(const float2*)(X + ((size_t)(r0 + r) * Tn + t) * In + kx);
      fma4(acc[r], x2.x, wa);
      fma4(acc[r], x2.y, wb);
    }
  }
  reduce_vs16(acc, c4, ksw, wv, part);
  __syncthreads();
  if (tid < 256) {
    const int r = tid >> 4, c = tid & 15;
    float u = part[0][r][c];
#pragma unroll
    for (int w = 1; w < 8; w++) u += part[w][r][c];
    const float av = alpha[0];
    v_out[(size_t)(r0 + r) * Hn + c0 + c] = av * hv - fmaxf(u + a1, 0.f);
  }
}

__global__ __launch_bounds__(512, 4) void k_phase2(
    float* __restrict__ h, const float* __restrict__ v_in,
    const float* __restrict__ WT, const float* __restrict__ alpha,
    const float* __restrict__ fc_w, float* __restrict__ out,
    float* __restrict__ hfin, int t, int last) {
  __shared__ float part[8][16][20];
  __shared__ float hn_s[16][16];
  const int ct = blockIdx.x & 63, rt = blockIdx.x >> 6;
  const int c0 = ct * 16, r0 = rt * 16;
  const int tid = threadIdx.x;
  const int c4 = tid & 3, kk = tid >> 2;
  const int col = c0 + 4 * c4;
  const int wv = tid >> 6, ksw = (tid >> 2) & 15;
  const float* vbase = v_in + (size_t)r0 * Hn;

  // prefetch epilogue operands
  float hv = 0.f, vv = 0.f;
  if (tid < 256) {
    const int r = tid >> 4, c = tid & 15;
    hv = h[(size_t)(r0 + r) * Hn + c0 + c];
    vv = vbase[(size_t)r * Hn + c0 + c];
  }

  float4 acc[16];
#pragma unroll
  for (int r = 0; r < 16; r++) acc[r] = {0.f, 0.f, 0.f, 0.f};
  gemm16g(vbase, WT, kk, col, acc);
  reduce_vs16(acc, c4, ksw, wv, part);
  __syncthreads();
  if (tid < 256) {
    const int r = tid >> 4, c = tid & 15;
    float u = part[0][r][c];
#pragma unroll
    for (int w = 1; w < 8; w++) u += part[w][r][c];
    const float av = alpha[0];
    const size_t hoff = (size_t)(r0 + r) * Hn + c0 + c;
    // phi = a*h - v; grad = a*v - (phi>0)*u; hn = h - LR*grad
    const float hn = hv - LR * (av * vv - ((av * hv - vv) > 0.f ? u : 0.f));
    h[hoff] = hn;
    if (last) hfin[hoff] = hn;
    hn_s[r][c] = hn;
  }
  __syncthreads();
  if (tid < 160) {  // FC partial over this block's 16 cols -> 160 atomics
    const int rr = tid / 10, c = tid % 10;
    float s = 0.f;
#pragma unroll
    for (int jj = 0; jj < 16; jj++)
      s += hn_s[rr][jj] * fc_w[(size_t)(c0 + jj) * Cn + c];
    atomicAdd(&out[((size_t)(r0 + rr) * Tn + t) * Cn + c], s);
  }
}

extern "C" void kernel_launch(void* const* d_in, const int* in_sizes, int n_in,
                              void* d_out, int out_size, void* d_ws, size_t ws_size,
                              hipStream_t stream) {
  const float* X      = (const float*)d_in[0];
  const float* hidden = (const float*)d_in[1];
  const float* alpha  = (const float*)d_in[2];
  const float* bias   = (const float*)d_in[3];
  const float* Wh     = (const float*)d_in[4];
  const float* Wx     = (const float*)d_in[5];
  const float* fc_w   = (const float*)d_in[6];
  const float* fc_b   = (const float*)d_in[7];
  float* out  = (float*)d_out;
  float* hfin = out + (size_t)Bsz * Tn * Cn;

  char* ws = (char*)d_ws;
  float* WhT   = (float*)ws;                        // 4 MB
  float* h_cur = WhT + (size_t)Hn * Hn;
  float* v_buf = h_cur + (size_t)Bsz * Hn;
  float* XW    = v_buf + (size_t)Bsz * Hn;          // 134 MB, [t][b][n]
  const size_t need =
      ((size_t)Hn * Hn + 2 * (size_t)Bsz * Hn + (size_t)Bsz * Tn * Hn) *
      sizeof(float);
  const bool pre = ws_size >= need;

  k_transpose<<<dim3(32, 32), 256, 0, stream>>>(Wh, WhT);
  k_init<<<(Bsz * Tn * Cn + 255) / 256, 256, 0, stream>>>(out, fc_b, h_cur,
                                                          hidden);
  if (pre) k_xw<<<8192, 256, 0, stream>>>(X, Wx, bias, XW);
  for (int t = 0; t < Tn; t++) {
    if (pre)
      k_phase1<1><<<512, 512, 0, stream>>>(h_cur, X, Wh, Wx, bias, alpha, XW,
                                           v_buf, t);
    else
      k_phase1<0><<<512, 512, 0, stream>>>(h_cur, X, Wh, Wx, bias, alpha, XW,
                                           v_buf, t);
    k_phase2<<<512, 512, 0, stream>>>(h_cur, v_buf, WhT, alpha, fc_w, out,
                                      hfin, t, t == Tn - 1);
  }
}

// Round 8
// 10809.278 us; speedup vs baseline: 1.5281x; 1.5281x over previous
//
#include <hip/hip_runtime.h>

// ODE_Vanilla scan: B=128, T=256, I=256, H=1024, C=10, fp32 throughout.
//   phase1: v = a*h - relu(h@Wh + XW[t])   (XW = X@Wx + b precomputed)
//   phase2: u = v@Wh^T; grad = a*v - (phi>0)*u; h -= LR*grad; out[b,t,:]=h@fc_w+fc_b
// R10 = R7 (proven 6.03 ms: direct-global rows, acc[8], value-split reduce,
// FC-in-phase2, multi-launch, grid 1024 = exactly 4/CU) plus:
//  (1) nontemporal W loads — W streams once/block; nt keeps it from evicting
//      the 128 KB/CU h working set out of the 32 KB L1 (h re-reads were
//      hitting L2 instead of L1);
//  (2) phase2 FC tail in-register: shfl-reduce over the 16 c-lanes replaces
//      hn_s LDS staging + second __syncthreads + 80-thread scalar loop.
// Hard-won constraints: acc <= 8 float4 (R6/R9 spills); grid <= co-resident
// count (R8); no in-kernel agent-scope barriers (R5: 266us each).

constexpr int Bsz = 128, Tn = 256, In = 256, Hn = 1024, Cn = 10;
constexpr float LR = 0.001f;

typedef float f4 __attribute__((ext_vector_type(4)));

__global__ __launch_bounds__(256) void k_transpose(const float* __restrict__ W,
                                                   float* __restrict__ WT) {
  __shared__ float tile[32][33];
  const int bx = blockIdx.x * 32, by = blockIdx.y * 32;
  const int tx = threadIdx.x & 31, ty = threadIdx.x >> 5;
#pragma unroll
  for (int dy = 0; dy < 32; dy += 8)
    tile[ty + dy][tx] = W[(size_t)(by + ty + dy) * Hn + bx + tx];
  __syncthreads();
#pragma unroll
  for (int dy = 0; dy < 32; dy += 8)
    WT[(size_t)(bx + ty + dy) * Hn + by + tx] = tile[tx][ty + dy];
}

__global__ __launch_bounds__(256) void k_init(float* __restrict__ out,
                                              const float* __restrict__ fc_b,
                                              float* __restrict__ h_cur,
                                              const float* __restrict__ hidden) {
  const int i = blockIdx.x * blockDim.x + threadIdx.x;
  if (i < Bsz * Tn * Cn) out[i] = fc_b[i % Cn];
  if (i < Bsz * Hn) h_cur[i] = hidden[i];
}

__device__ __forceinline__ void fma4(float4& a, float s, const float4& w) {
  a.x = fmaf(s, w.x, a.x);
  a.y = fmaf(s, w.y, a.y);
  a.z = fmaf(s, w.z, a.z);
  a.w = fmaf(s, w.w, a.w);
}

__device__ __forceinline__ void fma4v(float4& a, float s, const f4& w) {
  a.x = fmaf(s, w.x, a.x);
  a.y = fmaf(s, w.y, a.y);
  a.z = fmaf(s, w.z, a.z);
  a.w = fmaf(s, w.w, a.w);
}

__device__ __forceinline__ f4 ldnt(const float* p) {
  return __builtin_nontemporal_load((const f4*)p);
}

__device__ __forceinline__ float4 shfl4(float4 v, int m) {
  v.x = __shfl_xor(v.x, m, 64);
  v.y = __shfl_xor(v.y, m, 64);
  v.z = __shfl_xor(v.z, m, 64);
  v.w = __shfl_xor(v.w, m, 64);
  return v;
}

__device__ __forceinline__ float4 add4(float4 a, float4 b) {
  return make_float4(a.x + b.x, a.y + b.y, a.z + b.z, a.w + b.w);
}

// XW[t][b][n] = sum_k X[b][t][k]*Wx[k][n] + bias[n].
__global__ __launch_bounds__(256) void k_xw(const float* __restrict__ X,
                                            const float* __restrict__ Wx,
                                            const float* __restrict__ bias,
                                            float* __restrict__ xw) {
  const int nt = blockIdx.x & 15, mt = blockIdx.x >> 4;
  const int t = mt >> 1, b0 = (mt & 1) * 64;
  const int cl = threadIdx.x & 15, rg = threadIdx.x >> 4;
  const int col = nt * 64 + cl * 4;
  const int row = b0 + rg * 4;
  float4 acc0 = {0, 0, 0, 0}, acc1 = {0, 0, 0, 0}, acc2 = {0, 0, 0, 0},
         acc3 = {0, 0, 0, 0};
  const size_t xstride = (size_t)Tn * In;
  const float* xp = X + ((size_t)row * Tn + t) * In;
  const float* wp = Wx + col;
#pragma unroll 2
  for (int k = 0; k < In; k += 4) {
    const float4 x0 = *(const float4*)(xp + k);
    const float4 x1 = *(const float4*)(xp + xstride + k);
    const float4 x2 = *(const float4*)(xp + 2 * xstride + k);
    const float4 x3 = *(const float4*)(xp + 3 * xstride + k);
    const float4 w0 = *(const float4*)(wp + (size_t)k * Hn);
    const float4 w1 = *(const float4*)(wp + (size_t)(k + 1) * Hn);
    const float4 w2 = *(const float4*)(wp + (size_t)(k + 2) * Hn);
    const float4 w3 = *(const float4*)(wp + (size_t)(k + 3) * Hn);
    fma4(acc0, x0.x, w0); fma4(acc0, x0.y, w1); fma4(acc0, x0.z, w2); fma4(acc0, x0.w, w3);
    fma4(acc1, x1.x, w0); fma4(acc1, x1.y, w1); fma4(acc1, x1.z, w2); fma4(acc1, x1.w, w3);
    fma4(acc2, x2.x, w0); fma4(acc2, x2.y, w1); fma4(acc2, x2.z, w2); fma4(acc2, x2.w, w3);
    fma4(acc3, x3.x, w0); fma4(acc3, x3.y, w1); fma4(acc3, x3.z, w2); fma4(acc3, x3.w, w3);
  }
  const float4 b4 = *(const float4*)(bias + col);
  float4 o[4] = {acc0, acc1, acc2, acc3};
#pragma unroll
  for (int i = 0; i < 4; i++) {
    float4 v = o[i];
    v.x += b4.x; v.y += b4.y; v.z += b4.z; v.w += b4.w;
    *(float4*)(xw + ((size_t)t * Bsz + row + i) * Hn + col) = v;
  }
}

// 8-rows x 16-cols x K=1024 panel GEMM; thread = c4(4) x kk(64). Rows read
// straight from global (L2/L1-hot; c4-lanes broadcast-merge). W loads are
// NONTEMPORAL: single-use stream, don't evict h from L1.
__device__ __forceinline__ void gemm8g(const float* __restrict__ rows,
                                       const float* __restrict__ W, int kk,
                                       int col, float4 acc[8]) {
#pragma unroll
  for (int q = 0; q < 4; q++) {
    const int k = 4 * kk + 256 * q;
    const float* Wp = W + (size_t)k * Hn + col;
    const f4 w0 = ldnt(Wp);
    const f4 w1 = ldnt(Wp + Hn);
    const f4 w2 = ldnt(Wp + 2 * Hn);
    const f4 w3 = ldnt(Wp + 3 * Hn);
#pragma unroll
    for (int r = 0; r < 8; r++) {
      const float4 h4 = *(const float4*)(rows + (size_t)r * Hn + k);
      fma4v(acc[r], h4.x, w0);
      fma4v(acc[r], h4.y, w1);
      fma4v(acc[r], h4.z, w2);
      fma4v(acc[r], h4.w, w3);
    }
  }
}

// Value-splitting reduce over ks lane bits 2..5 (validated R5/R7): 30 shfl.
// Lane ends owning float2 at (r_own, 4*c4 + 2*u4); writes part[wv].
__device__ __forceinline__ void reduce_vs(float4 acc[8], int c4, int ksw,
                                          int wv, float (*part)[8][16]) {
  const bool u1 = ksw & 1;
#pragma unroll
  for (int i = 0; i < 4; i++) {
    const float4 snd = u1 ? acc[i] : acc[i + 4];
    const float4 kp = u1 ? acc[i + 4] : acc[i];
    acc[i] = add4(kp, shfl4(snd, 4));
  }
  const bool u2 = ksw & 2;
#pragma unroll
  for (int i = 0; i < 2; i++) {
    const float4 snd = u2 ? acc[i] : acc[i + 2];
    const float4 kp = u2 ? acc[i + 2] : acc[i];
    acc[i] = add4(kp, shfl4(snd, 8));
  }
  const bool u3 = ksw & 4;
  {
    const float4 snd = u3 ? acc[0] : acc[1];
    const float4 kp = u3 ? acc[1] : acc[0];
    acc[0] = add4(kp, shfl4(snd, 16));
  }
  const bool u4 = ksw & 8;
  float sx = u4 ? acc[0].x : acc[0].z;
  float sy = u4 ? acc[0].y : acc[0].w;
  const float kx = u4 ? acc[0].z : acc[0].x;
  const float ky = u4 ? acc[0].w : acc[0].y;
  sx = __shfl_xor(sx, 32, 64);
  sy = __shfl_xor(sy, 32, 64);
  const int r_own = ((ksw & 1) << 2) | (ksw & 2) | ((ksw >> 2) & 1);
  const int c_own = 4 * c4 + (u4 ? 2 : 0);
  *(float2*)&part[wv][r_own][c_own] = make_float2(kx + sx, ky + sy);
}

// grid 1024 = rt(16, 8 rows) x ct(64, 16 cols); thread = c4(4) x kk(64).
template <int PRE>
__global__ __launch_bounds__(256, 4) void k_phase1(
    const float* __restrict__ h, const float* __restrict__ X,
    const float* __restrict__ Wh, const float* __restrict__ Wx,
    const float* __restrict__ bias, const float* __restrict__ alpha,
    const float* __restrict__ xw, float* __restrict__ v_out, int t) {
  __shared__ float part[4][8][16];
  const int ct = blockIdx.x & 63, rt = blockIdx.x >> 6;
  const int c0 = ct * 16, r0 = rt * 8;
  const int tid = threadIdx.x;
  const int c4 = tid & 3, kk = tid >> 2;
  const int col = c0 + 4 * c4;
  const int wv = tid >> 6, ksw = (tid & 63) >> 2;
  const float* hbase = h + (size_t)r0 * Hn;
  const float av = alpha[0];  // hoisted scalar load

  float4 acc[8];
#pragma unroll
  for (int r = 0; r < 8; r++) acc[r] = {0.f, 0.f, 0.f, 0.f};
  gemm8g(hbase, Wh, kk, col, acc);
  if (!PRE) {  // x@Wx inline: thread kk owns Wx row-quad 4kk (I=256=64*4)
    const int kx = 4 * kk;
    const float* Wp = Wx + (size_t)kx * Hn + col;
    const f4 w0 = ldnt(Wp);
    const f4 w1 = ldnt(Wp + Hn);
    const f4 w2 = ldnt(Wp + 2 * Hn);
    const f4 w3 = ldnt(Wp + 3 * Hn);
#pragma unroll
    for (int r = 0; r < 8; r++) {
      const float4 x4 =
          *(const float4*)(X + ((size_t)(r0 + r) * Tn + t) * In + kx);
      fma4v(acc[r], x4.x, w0);
      fma4v(acc[r], x4.y, w1);
      fma4v(acc[r], x4.z, w2);
      fma4v(acc[r], x4.w, w3);
    }
  }
  reduce_vs(acc, c4, ksw, wv, part);
  __syncthreads();
  if (tid < 128) {
    const int r = tid >> 4, c = tid & 15;
    const float u =
        part[0][r][c] + part[1][r][c] + part[2][r][c] + part[3][r][c];
    const float a1 =
        PRE ? xw[((size_t)t * Bsz + r0 + r) * Hn + c0 + c] : bias[c0 + c];
    const float hv = hbase[(size_t)r * Hn + c0 + c];
    v_out[(size_t)(r0 + r) * Hn + c0 + c] = av * hv - fmaxf(u + a1, 0.f);
  }
}

__global__ __launch_bounds__(256, 4) void k_phase2(
    float* __restrict__ h, const float* __restrict__ v_in,
    const float* __restrict__ WT, const float* __restrict__ alpha,
    const float* __restrict__ fc_w, float* __restrict__ out,
    float* __restrict__ hfin, int t, int last) {
  __shared__ float part[4][8][16];
  const int ct = blockIdx.x & 63, rt = blockIdx.x >> 6;
  const int c0 = ct * 16, r0 = rt * 8;
  const int tid = threadIdx.x;
  const int c4 = tid & 3, kk = tid >> 2;
  const int col = c0 + 4 * c4;
  const int wv = tid >> 6, ksw = (tid & 63) >> 2;
  const float* vbase = v_in + (size_t)r0 * Hn;
  const float av = alpha[0];

  float4 acc[8];
#pragma unroll
  for (int r = 0; r < 8; r++) acc[r] = {0.f, 0.f, 0.f, 0.f};
  gemm8g(vbase, WT, kk, col, acc);
  reduce_vs(acc, c4, ksw, wv, part);
  __syncthreads();
  if (tid < 128) {
    const int r = tid >> 4, c = tid & 15;
    const float u =
        part[0][r][c] + part[1][r][c] + part[2][r][c] + part[3][r][c];
    const size_t hoff = (size_t)(r0 + r) * Hn + c0 + c;
    const float vv = vbase[(size_t)r * Hn + c0 + c];
    const float hv = h[hoff];
    // phi = a*h - v; grad = a*v - (phi>0)*u; hn = h - LR*grad
    const float hn = hv - LR * (av * vv - ((av * hv - vv) > 0.f ? u : 0.f));
    h[hoff] = hn;
    if (last) hfin[hoff] = hn;
    // FC in-register: p[cc] = sum over the 16 c-lanes of hn * fc_w[c0+c][cc]
    float p[Cn];
    const float* fw = fc_w + (size_t)(c0 + c) * Cn;
#pragma unroll
    for (int cc = 0; cc < Cn; cc++) p[cc] = hn * fw[cc];
#pragma unroll
    for (int m = 1; m <= 8; m <<= 1)
#pragma unroll
      for (int cc = 0; cc < Cn; cc++) p[cc] += __shfl_xor(p[cc], m, 64);
    if (c == 0) {
      float* op = out + ((size_t)(r0 + r) * Tn + t) * Cn;
#pragma unroll
      for (int cc = 0; cc < Cn; cc++) atomicAdd(op + cc, p[cc]);
    }
  }
}

extern "C" void kernel_launch(void* const* d_in, const int* in_sizes, int n_in,
                              void* d_out, int out_size, void* d_ws, size_t ws_size,
                              hipStream_t stream) {
  const float* X      = (const float*)d_in[0];
  const float* hidden = (const float*)d_in[1];
  const float* alpha  = (const float*)d_in[2];
  const float* bias   = (const float*)d_in[3];
  const float* Wh     = (const float*)d_in[4];
  const float* Wx     = (const float*)d_in[5];
  const float* fc_w   = (const float*)d_in[6];
  const float* fc_b   = (const float*)d_in[7];
  float* out  = (float*)d_out;
  float* hfin = out + (size_t)Bsz * Tn * Cn;

  char* ws = (char*)d_ws;
  float* WhT   = (float*)ws;                        // 4 MB
  float* h_cur = WhT + (size_t)Hn * Hn;
  float* v_buf = h_cur + (size_t)Bsz * Hn;
  float* XW    = v_buf + (size_t)Bsz * Hn;          // 134 MB, [t][b][n]
  const size_t need =
      ((size_t)Hn * Hn + 2 * (size_t)Bsz * Hn + (size_t)Bsz * Tn * Hn) *
      sizeof(float);
  const bool pre = ws_size >= need;

  k_transpose<<<dim3(32, 32), 256, 0, stream>>>(Wh, WhT);
  k_init<<<(Bsz * Tn * Cn + 255) / 256, 256, 0, stream>>>(out, fc_b, h_cur,
                                                          hidden);
  if (pre) k_xw<<<8192, 256, 0, stream>>>(X, Wx, bias, XW);
  for (int t = 0; t < Tn; t++) {
    if (pre)
      k_phase1<1><<<1024, 256, 0, stream>>>(h_cur, X, Wh, Wx, bias, alpha, XW,
                                            v_buf, t);
    else
      k_phase1<0><<<1024, 256, 0, stream>>>(h_cur, X, Wh, Wx, bias, alpha, XW,
                                            v_buf, t);
    k_phase2<<<1024, 256, 0, stream>>>(h_cur, v_buf, WhT, alpha, fc_w, out,
                                       hfin, t, t == Tn - 1);
  }
}

// Round 9
// 9630.172 us; speedup vs baseline: 1.7152x; 1.1224x over previous
//
#include <hip/hip_runtime.h>

// ODE_Vanilla scan: B=128, T=256, I=256, H=1024, C=10, fp32 throughout.
//   phase1: v = a*h - relu(h@Wh + XW[t])   (XW = X@Wx + b precomputed)
//   phase2: u = v@Wh^T; grad = a*v - (phi>0)*u; h -= LR*grad; out[b,t,:]=h@fc_w+fc_b
// R11 = R7 (proven 6.03 ms) + two tail shavings, NO nt loads (R10: nt
// bypasses L2 -> W re-fetched from L3 every dispatch, +4.8 ms):
//  (1) in-register FC tail in phase2 (verified correct in R10): shfl-reduce
//      over the 16 c-lanes replaces hn_s LDS staging + 2nd __syncthreads;
//  (2) epilogue operands (xw/bias, hv, vv) prefetched BEFORE the GEMM so
//      their ~500cy latency hides under compute instead of sitting on the
//      dispatch tail after the reduce.
// Hard constraints (measured): acc <= 8 float4 (R6/R9 spills); grid <= 1024
// co-resident (R8); no in-kernel agent-scope barriers (R5: 266us each);
// plain cached W loads (R10: nt kills L2 reuse).

constexpr int Bsz = 128, Tn = 256, In = 256, Hn = 1024, Cn = 10;
constexpr float LR = 0.001f;

__global__ __launch_bounds__(256) void k_transpose(const float* __restrict__ W,
                                                   float* __restrict__ WT) {
  __shared__ float tile[32][33];
  const int bx = blockIdx.x * 32, by = blockIdx.y * 32;
  const int tx = threadIdx.x & 31, ty = threadIdx.x >> 5;
#pragma unroll
  for (int dy = 0; dy < 32; dy += 8)
    tile[ty + dy][tx] = W[(size_t)(by + ty + dy) * Hn + bx + tx];
  __syncthreads();
#pragma unroll
  for (int dy = 0; dy < 32; dy += 8)
    WT[(size_t)(bx + ty + dy) * Hn + by + tx] = tile[tx][ty + dy];
}

__global__ __launch_bounds__(256) void k_init(float* __restrict__ out,
                                              const float* __restrict__ fc_b,
                                              float* __restrict__ h_cur,
                                              const float* __restrict__ hidden) {
  const int i = blockIdx.x * blockDim.x + threadIdx.x;
  if (i < Bsz * Tn * Cn) out[i] = fc_b[i % Cn];
  if (i < Bsz * Hn) h_cur[i] = hidden[i];
}

__device__ __forceinline__ void fma4(float4& a, float s, const float4& w) {
  a.x = fmaf(s, w.x, a.x);
  a.y = fmaf(s, w.y, a.y);
  a.z = fmaf(s, w.z, a.z);
  a.w = fmaf(s, w.w, a.w);
}

__device__ __forceinline__ float4 shfl4(float4 v, int m) {
  v.x = __shfl_xor(v.x, m, 64);
  v.y = __shfl_xor(v.y, m, 64);
  v.z = __shfl_xor(v.z, m, 64);
  v.w = __shfl_xor(v.w, m, 64);
  return v;
}

__device__ __forceinline__ float4 add4(float4 a, float4 b) {
  return make_float4(a.x + b.x, a.y + b.y, a.z + b.z, a.w + b.w);
}

// XW[t][b][n] = sum_k X[b][t][k]*Wx[k][n] + bias[n].
__global__ __launch_bounds__(256) void k_xw(const float* __restrict__ X,
                                            const float* __restrict__ Wx,
                                            const float* __restrict__ bias,
                                            float* __restrict__ xw) {
  const int nt = blockIdx.x & 15, mt = blockIdx.x >> 4;
  const int t = mt >> 1, b0 = (mt & 1) * 64;
  const int cl = threadIdx.x & 15, rg = threadIdx.x >> 4;
  const int col = nt * 64 + cl * 4;
  const int row = b0 + rg * 4;
  float4 acc0 = {0, 0, 0, 0}, acc1 = {0, 0, 0, 0}, acc2 = {0, 0, 0, 0},
         acc3 = {0, 0, 0, 0};
  const size_t xstride = (size_t)Tn * In;
  const float* xp = X + ((size_t)row * Tn + t) * In;
  const float* wp = Wx + col;
#pragma unroll 2
  for (int k = 0; k < In; k += 4) {
    const float4 x0 = *(const float4*)(xp + k);
    const float4 x1 = *(const float4*)(xp + xstride + k);
    const float4 x2 = *(const float4*)(xp + 2 * xstride + k);
    const float4 x3 = *(const float4*)(xp + 3 * xstride + k);
    const float4 w0 = *(const float4*)(wp + (size_t)k * Hn);
    const float4 w1 = *(const float4*)(wp + (size_t)(k + 1) * Hn);
    const float4 w2 = *(const float4*)(wp + (size_t)(k + 2) * Hn);
    const float4 w3 = *(const float4*)(wp + (size_t)(k + 3) * Hn);
    fma4(acc0, x0.x, w0); fma4(acc0, x0.y, w1); fma4(acc0, x0.z, w2); fma4(acc0, x0.w, w3);
    fma4(acc1, x1.x, w0); fma4(acc1, x1.y, w1); fma4(acc1, x1.z, w2); fma4(acc1, x1.w, w3);
    fma4(acc2, x2.x, w0); fma4(acc2, x2.y, w1); fma4(acc2, x2.z, w2); fma4(acc2, x2.w, w3);
    fma4(acc3, x3.x, w0); fma4(acc3, x3.y, w1); fma4(acc3, x3.z, w2); fma4(acc3, x3.w, w3);
  }
  const float4 b4 = *(const float4*)(bias + col);
  float4 o[4] = {acc0, acc1, acc2, acc3};
#pragma unroll
  for (int i = 0; i < 4; i++) {
    float4 v = o[i];
    v.x += b4.x; v.y += b4.y; v.z += b4.z; v.w += b4.w;
    *(float4*)(xw + ((size_t)t * Bsz + row + i) * Hn + col) = v;
  }
}

// 8-rows x 16-cols x K=1024 panel GEMM; thread = c4(4) x kk(64). Rows read
// straight from global (L2/L1-hot; c4-lanes broadcast-merge). Plain cached
// W loads (L2-resident slice per XCD).
__device__ __forceinline__ void gemm8g(const float* __restrict__ rows,
                                       const float* __restrict__ W, int kk,
                                       int col, float4 acc[8]) {
#pragma unroll
  for (int q = 0; q < 4; q++) {
    const int k = 4 * kk + 256 * q;
    const float* Wp = W + (size_t)k * Hn + col;
    const float4 w0 = *(const float4*)(Wp);
    const float4 w1 = *(const float4*)(Wp + Hn);
    const float4 w2 = *(const float4*)(Wp + 2 * Hn);
    const float4 w3 = *(const float4*)(Wp + 3 * Hn);
#pragma unroll
    for (int r = 0; r < 8; r++) {
      const float4 h4 = *(const float4*)(rows + (size_t)r * Hn + k);
      fma4(acc[r], h4.x, w0);
      fma4(acc[r], h4.y, w1);
      fma4(acc[r], h4.z, w2);
      fma4(acc[r], h4.w, w3);
    }
  }
}

// Value-splitting reduce over ks lane bits 2..5 (validated R5/R7): 30 shfl.
// Lane ends owning float2 at (r_own, 4*c4 + 2*u4); writes part[wv].
__device__ __forceinline__ void reduce_vs(float4 acc[8], int c4, int ksw,
                                          int wv, float (*part)[8][16]) {
  const bool u1 = ksw & 1;
#pragma unroll
  for (int i = 0; i < 4; i++) {
    const float4 snd = u1 ? acc[i] : acc[i + 4];
    const float4 kp = u1 ? acc[i + 4] : acc[i];
    acc[i] = add4(kp, shfl4(snd, 4));
  }
  const bool u2 = ksw & 2;
#pragma unroll
  for (int i = 0; i < 2; i++) {
    const float4 snd = u2 ? acc[i] : acc[i + 2];
    const float4 kp = u2 ? acc[i + 2] : acc[i];
    acc[i] = add4(kp, shfl4(snd, 8));
  }
  const bool u3 = ksw & 4;
  {
    const float4 snd = u3 ? acc[0] : acc[1];
    const float4 kp = u3 ? acc[1] : acc[0];
    acc[0] = add4(kp, shfl4(snd, 16));
  }
  const bool u4 = ksw & 8;
  float sx = u4 ? acc[0].x : acc[0].z;
  float sy = u4 ? acc[0].y : acc[0].w;
  const float kx = u4 ? acc[0].z : acc[0].x;
  const float ky = u4 ? acc[0].w : acc[0].y;
  sx = __shfl_xor(sx, 32, 64);
  sy = __shfl_xor(sy, 32, 64);
  const int r_own = ((ksw & 1) << 2) | (ksw & 2) | ((ksw >> 2) & 1);
  const int c_own = 4 * c4 + (u4 ? 2 : 0);
  *(float2*)&part[wv][r_own][c_own] = make_float2(kx + sx, ky + sy);
}

// grid 1024 = rt(16, 8 rows) x ct(64, 16 cols); thread = c4(4) x kk(64).
template <int PRE>
__global__ __launch_bounds__(256, 4) void k_phase1(
    const float* __restrict__ h, const float* __restrict__ X,
    const float* __restrict__ Wh, const float* __restrict__ Wx,
    const float* __restrict__ bias, const float* __restrict__ alpha,
    const float* __restrict__ xw, float* __restrict__ v_out, int t) {
  __shared__ float part[4][8][16];
  const int ct = blockIdx.x & 63, rt = blockIdx.x >> 6;
  const int c0 = ct * 16, r0 = rt * 8;
  const int tid = threadIdx.x;
  const int c4 = tid & 3, kk = tid >> 2;
  const int col = c0 + 4 * c4;
  const int wv = tid >> 6, ksw = (tid & 63) >> 2;
  const float* hbase = h + (size_t)r0 * Hn;
  const float av = alpha[0];

  // prefetch epilogue operands: latency hides under the GEMM
  float a1 = 0.f, hv = 0.f;
  if (tid < 128) {
    const int r = tid >> 4, c = tid & 15;
    a1 = PRE ? xw[((size_t)t * Bsz + r0 + r) * Hn + c0 + c] : bias[c0 + c];
    hv = hbase[(size_t)r * Hn + c0 + c];
  }

  float4 acc[8];
#pragma unroll
  for (int r = 0; r < 8; r++) acc[r] = {0.f, 0.f, 0.f, 0.f};
  gemm8g(hbase, Wh, kk, col, acc);
  if (!PRE) {  // x@Wx inline: thread kk owns Wx row-quad 4kk (I=256=64*4)
    const int kx = 4 * kk;
    const float* Wp = Wx + (size_t)kx * Hn + col;
    const float4 w0 = *(const float4*)(Wp);
    const float4 w1 = *(const float4*)(Wp + Hn);
    const float4 w2 = *(const float4*)(Wp + 2 * Hn);
    const float4 w3 = *(const float4*)(Wp + 3 * Hn);
#pragma unroll
    for (int r = 0; r < 8; r++) {
      const float4 x4 =
          *(const float4*)(X + ((size_t)(r0 + r) * Tn + t) * In + kx);
      fma4(acc[r], x4.x, w0);
      fma4(acc[r], x4.y, w1);
      fma4(acc[r], x4.z, w2);
      fma4(acc[r], x4.w, w3);
    }
  }
  reduce_vs(acc, c4, ksw, wv, part);
  __syncthreads();
  if (tid < 128) {
    const int r = tid >> 4, c = tid & 15;
    const float u =
        part[0][r][c] + part[1][r][c] + part[2][r][c] + part[3][r][c];
    v_out[(size_t)(r0 + r) * Hn + c0 + c] = av * hv - fmaxf(u + a1, 0.f);
  }
}

__global__ __launch_bounds__(256, 4) void k_phase2(
    float* __restrict__ h, const float* __restrict__ v_in,
    const float* __restrict__ WT, const float* __restrict__ alpha,
    const float* __restrict__ fc_w, float* __restrict__ out,
    float* __restrict__ hfin, int t, int last) {
  __shared__ float part[4][8][16];
  const int ct = blockIdx.x & 63, rt = blockIdx.x >> 6;
  const int c0 = ct * 16, r0 = rt * 8;
  const int tid = threadIdx.x;
  const int c4 = tid & 3, kk = tid >> 2;
  const int col = c0 + 4 * c4;
  const int wv = tid >> 6, ksw = (tid & 63) >> 2;
  const float* vbase = v_in + (size_t)r0 * Hn;
  const float av = alpha[0];

  // prefetch epilogue operands (h not written until after the reduce; v_in
  // is read-only here) — hides their latency under the GEMM
  float hv = 0.f, vv = 0.f;
  if (tid < 128) {
    const int r = tid >> 4, c = tid & 15;
    hv = h[(size_t)(r0 + r) * Hn + c0 + c];
    vv = vbase[(size_t)r * Hn + c0 + c];
  }

  float4 acc[8];
#pragma unroll
  for (int r = 0; r < 8; r++) acc[r] = {0.f, 0.f, 0.f, 0.f};
  gemm8g(vbase, WT, kk, col, acc);
  reduce_vs(acc, c4, ksw, wv, part);
  __syncthreads();
  if (tid < 128) {
    const int r = tid >> 4, c = tid & 15;
    const float u =
        part[0][r][c] + part[1][r][c] + part[2][r][c] + part[3][r][c];
    const size_t hoff = (size_t)(r0 + r) * Hn + c0 + c;
    // phi = a*h - v; grad = a*v - (phi>0)*u; hn = h - LR*grad
    const float hn = hv - LR * (av * vv - ((av * hv - vv) > 0.f ? u : 0.f));
    h[hoff] = hn;
    if (last) hfin[hoff] = hn;
    // FC in-register (verified in R10): butterfly over the 16 c-lanes
    float p[Cn];
    const float* fw = fc_w + (size_t)(c0 + c) * Cn;
#pragma unroll
    for (int cc = 0; cc < Cn; cc++) p[cc] = hn * fw[cc];
#pragma unroll
    for (int m = 1; m <= 8; m <<= 1)
#pragma unroll
      for (int cc = 0; cc < Cn; cc++) p[cc] += __shfl_xor(p[cc], m, 64);
    if (c == 0) {
      float* op = out + ((size_t)(r0 + r) * Tn + t) * Cn;
#pragma unroll
      for (int cc = 0; cc < Cn; cc++) atomicAdd(op + cc, p[cc]);
    }
  }
}

extern "C" void kernel_launch(void* const* d_in, const int* in_sizes, int n_in,
                              void* d_out, int out_size, void* d_ws, size_t ws_size,
                              hipStream_t stream) {
  const float* X      = (const float*)d_in[0];
  const float* hidden = (const float*)d_in[1];
  const float* alpha  = (const float*)d_in[2];
  const float* bias   = (const float*)d_in[3];
  const float* Wh     = (const float*)d_in[4];
  const float* Wx     = (const float*)d_in[5];
  const float* fc_w   = (const float*)d_in[6];
  const float* fc_b   = (const float*)d_in[7];
  float* out  = (float*)d_out;
  float* hfin = out + (size_t)Bsz * Tn * Cn;

  char* ws = (char*)d_ws;
  float* WhT   = (float*)ws;                        // 4 MB
  float* h_cur = WhT + (size_t)Hn * Hn;
  float* v_buf = h_cur + (size_t)Bsz * Hn;
  float* XW    = v_buf + (size_t)Bsz * Hn;          // 134 MB, [t][b][n]
  const size_t need =
      ((size_t)Hn * Hn + 2 * (size_t)Bsz * Hn + (size_t)Bsz * Tn * Hn) *
      sizeof(float);
  const bool pre = ws_size >= need;

  k_transpose<<<dim3(32, 32), 256, 0, stream>>>(Wh, WhT);
  k_init<<<(Bsz * Tn * Cn + 255) / 256, 256, 0, stream>>>(out, fc_b, h_cur,
                                                          hidden);
  if (pre) k_xw<<<8192, 256, 0, stream>>>(X, Wx, bias, XW);
  for (int t = 0; t < Tn; t++) {
    if (pre)
      k_phase1<1><<<1024, 256, 0, stream>>>(h_cur, X, Wh, Wx, bias, alpha, XW,
                                            v_buf, t);
    else
      k_phase1<0><<<1024, 256, 0, stream>>>(h_cur, X, Wh, Wx, bias, alpha, XW,
                                            v_buf, t);
    k_phase2<<<1024, 256, 0, stream>>>(h_cur, v_buf, WhT, alpha, fc_w, out,
                                       hfin, t, t == Tn - 1);
  }
}

// Round 10
// 5952.961 us; speedup vs baseline: 2.7746x; 1.6177x over previous
//
#include <hip/hip_runtime.h>

// ODE_Vanilla scan: B=128, T=256, I=256, H=1024, C=10, fp32 throughout.
//   phase1: v = a*h - relu(h@Wh + XW[t])   (XW = X@Wx + b precomputed)
//   phase2: u = v@Wh^T; grad = a*v - (phi>0)*u; h -= LR*grad; out[b,t,:]=h@fc_w+fc_b
// R12 = byte-exact R7 (proven 6.03 ms) + ONE delta: epilogue operand loads
// (xw/bias+hv in p1, hv+vv in p2) hoisted BEFORE the GEMM so their L2/L3
// latency hides under compute instead of sitting after the reduce+sync.
// FC tail restored to R7's LDS form (R10+R11 both regressed with the
// in-register FC variant — common-element analysis fingers it, not nt).
// Hard constraints (measured): acc <= 8 float4 (R6/R9 spills); grid <= 1024
// co-resident (R8); no in-kernel agent-scope barriers (R5: 266us each);
// plain cached W loads (R10); one variable per round.

constexpr int Bsz = 128, Tn = 256, In = 256, Hn = 1024, Cn = 10;
constexpr float LR = 0.001f;

__global__ __launch_bounds__(256) void k_transpose(const float* __restrict__ W,
                                                   float* __restrict__ WT) {
  __shared__ float tile[32][33];
  const int bx = blockIdx.x * 32, by = blockIdx.y * 32;
  const int tx = threadIdx.x & 31, ty = threadIdx.x >> 5;
#pragma unroll
  for (int dy = 0; dy < 32; dy += 8)
    tile[ty + dy][tx] = W[(size_t)(by + ty + dy) * Hn + bx + tx];
  __syncthreads();
#pragma unroll
  for (int dy = 0; dy < 32; dy += 8)
    WT[(size_t)(bx + ty + dy) * Hn + by + tx] = tile[tx][ty + dy];
}

__global__ __launch_bounds__(256) void k_init(float* __restrict__ out,
                                              const float* __restrict__ fc_b,
                                              float* __restrict__ h_cur,
                                              const float* __restrict__ hidden) {
  const int i = blockIdx.x * blockDim.x + threadIdx.x;
  if (i < Bsz * Tn * Cn) out[i] = fc_b[i % Cn];
  if (i < Bsz * Hn) h_cur[i] = hidden[i];
}

__device__ __forceinline__ void fma4(float4& a, float s, const float4& w) {
  a.x = fmaf(s, w.x, a.x);
  a.y = fmaf(s, w.y, a.y);
  a.z = fmaf(s, w.z, a.z);
  a.w = fmaf(s, w.w, a.w);
}

__device__ __forceinline__ float4 shfl4(float4 v, int m) {
  v.x = __shfl_xor(v.x, m, 64);
  v.y = __shfl_xor(v.y, m, 64);
  v.z = __shfl_xor(v.z, m, 64);
  v.w = __shfl_xor(v.w, m, 64);
  return v;
}

__device__ __forceinline__ float4 add4(float4 a, float4 b) {
  return make_float4(a.x + b.x, a.y + b.y, a.z + b.z, a.w + b.w);
}

// XW[t][b][n] = sum_k X[b][t][k]*Wx[k][n] + bias[n].
__global__ __launch_bounds__(256) void k_xw(const float* __restrict__ X,
                                            const float* __restrict__ Wx,
                                            const float* __restrict__ bias,
                                            float* __restrict__ xw) {
  const int nt = blockIdx.x & 15, mt = blockIdx.x >> 4;
  const int t = mt >> 1, b0 = (mt & 1) * 64;
  const int cl = threadIdx.x & 15, rg = threadIdx.x >> 4;
  const int col = nt * 64 + cl * 4;
  const int row = b0 + rg * 4;
  float4 acc0 = {0, 0, 0, 0}, acc1 = {0, 0, 0, 0}, acc2 = {0, 0, 0, 0},
         acc3 = {0, 0, 0, 0};
  const size_t xstride = (size_t)Tn * In;
  const float* xp = X + ((size_t)row * Tn + t) * In;
  const float* wp = Wx + col;
#pragma unroll 2
  for (int k = 0; k < In; k += 4) {
    const float4 x0 = *(const float4*)(xp + k);
    const float4 x1 = *(const float4*)(xp + xstride + k);
    const float4 x2 = *(const float4*)(xp + 2 * xstride + k);
    const float4 x3 = *(const float4*)(xp + 3 * xstride + k);
    const float4 w0 = *(const float4*)(wp + (size_t)k * Hn);
    const float4 w1 = *(const float4*)(wp + (size_t)(k + 1) * Hn);
    const float4 w2 = *(const float4*)(wp + (size_t)(k + 2) * Hn);
    const float4 w3 = *(const float4*)(wp + (size_t)(k + 3) * Hn);
    fma4(acc0, x0.x, w0); fma4(acc0, x0.y, w1); fma4(acc0, x0.z, w2); fma4(acc0, x0.w, w3);
    fma4(acc1, x1.x, w0); fma4(acc1, x1.y, w1); fma4(acc1, x1.z, w2); fma4(acc1, x1.w, w3);
    fma4(acc2, x2.x, w0); fma4(acc2, x2.y, w1); fma4(acc2, x2.z, w2); fma4(acc2, x2.w, w3);
    fma4(acc3, x3.x, w0); fma4(acc3, x3.y, w1); fma4(acc3, x3.z, w2); fma4(acc3, x3.w, w3);
  }
  const float4 b4 = *(const float4*)(bias + col);
  float4 o[4] = {acc0, acc1, acc2, acc3};
#pragma unroll
  for (int i = 0; i < 4; i++) {
    float4 v = o[i];
    v.x += b4.x; v.y += b4.y; v.z += b4.z; v.w += b4.w;
    *(float4*)(xw + ((size_t)t * Bsz + row + i) * Hn + col) = v;
  }
}

// 8-rows x 16-cols x K=1024 panel GEMM; thread = c4(4) x kk(64). Rows read
// straight from global (L2/L1-hot; c4-lanes broadcast-merge).
__device__ __forceinline__ void gemm8g(const float* __restrict__ rows,
                                       const float* __restrict__ W, int kk,
                                       int col, float4 acc[8]) {
#pragma unroll
  for (int q = 0; q < 4; q++) {
    const int k = 4 * kk + 256 * q;
    const float* Wp = W + (size_t)k * Hn + col;
    const float4 w0 = *(const float4*)(Wp);
    const float4 w1 = *(const float4*)(Wp + Hn);
    const float4 w2 = *(const float4*)(Wp + 2 * Hn);
    const float4 w3 = *(const float4*)(Wp + 3 * Hn);
#pragma unroll
    for (int r = 0; r < 8; r++) {
      const float4 h4 = *(const float4*)(rows + (size_t)r * Hn + k);
      fma4(acc[r], h4.x, w0);
      fma4(acc[r], h4.y, w1);
      fma4(acc[r], h4.z, w2);
      fma4(acc[r], h4.w, w3);
    }
  }
}

// Value-splitting reduce over ks lane bits 2..5 (validated R5/R7): 30 shfl.
// Lane ends owning float2 at (r_own, 4*c4 + 2*u4); writes part[wv].
__device__ __forceinline__ void reduce_vs(float4 acc[8], int c4, int ksw,
                                          int wv, float (*part)[8][16]) {
  const bool u1 = ksw & 1;
#pragma unroll
  for (int i = 0; i < 4; i++) {
    const float4 snd = u1 ? acc[i] : acc[i + 4];
    const float4 kp = u1 ? acc[i + 4] : acc[i];
    acc[i] = add4(kp, shfl4(snd, 4));
  }
  const bool u2 = ksw & 2;
#pragma unroll
  for (int i = 0; i < 2; i++) {
    const float4 snd = u2 ? acc[i] : acc[i + 2];
    const float4 kp = u2 ? acc[i + 2] : acc[i];
    acc[i] = add4(kp, shfl4(snd, 8));
  }
  const bool u3 = ksw & 4;
  {
    const float4 snd = u3 ? acc[0] : acc[1];
    const float4 kp = u3 ? acc[1] : acc[0];
    acc[0] = add4(kp, shfl4(snd, 16));
  }
  const bool u4 = ksw & 8;
  float sx = u4 ? acc[0].x : acc[0].z;
  float sy = u4 ? acc[0].y : acc[0].w;
  const float kx = u4 ? acc[0].z : acc[0].x;
  const float ky = u4 ? acc[0].w : acc[0].y;
  sx = __shfl_xor(sx, 32, 64);
  sy = __shfl_xor(sy, 32, 64);
  const int r_own = ((ksw & 1) << 2) | (ksw & 2) | ((ksw >> 2) & 1);
  const int c_own = 4 * c4 + (u4 ? 2 : 0);
  *(float2*)&part[wv][r_own][c_own] = make_float2(kx + sx, ky + sy);
}

// grid 1024 = rt(16, 8 rows) x ct(64, 16 cols); thread = c4(4) x kk(64).
template <int PRE>
__global__ __launch_bounds__(256, 4) void k_phase1(
    const float* __restrict__ h, const float* __restrict__ X,
    const float* __restrict__ Wh, const float* __restrict__ Wx,
    const float* __restrict__ bias, const float* __restrict__ alpha,
    const float* __restrict__ xw, float* __restrict__ v_out, int t) {
  __shared__ float part[4][8][16];
  const int ct = blockIdx.x & 63, rt = blockIdx.x >> 6;
  const int c0 = ct * 16, r0 = rt * 8;
  const int tid = threadIdx.x;
  const int c4 = tid & 3, kk = tid >> 2;
  const int col = c0 + 4 * c4;
  const int wv = tid >> 6, ksw = (tid & 63) >> 2;
  const float* hbase = h + (size_t)r0 * Hn;

  // DELTA vs R7: epilogue operands loaded early; latency hides under GEMM.
  float a1 = 0.f, hv = 0.f;
  if (tid < 128) {
    const int r = tid >> 4, c = tid & 15;
    a1 = PRE ? xw[((size_t)t * Bsz + r0 + r) * Hn + c0 + c] : bias[c0 + c];
    hv = hbase[(size_t)r * Hn + c0 + c];
  }

  float4 acc[8];
#pragma unroll
  for (int r = 0; r < 8; r++) acc[r] = {0.f, 0.f, 0.f, 0.f};
  gemm8g(hbase, Wh, kk, col, acc);
  if (!PRE) {  // x@Wx inline: thread kk owns Wx row-quad 4kk (I=256=64*4)
    const int kx = 4 * kk;
    const float* Wp = Wx + (size_t)kx * Hn + col;
    const float4 w0 = *(const float4*)(Wp);
    const float4 w1 = *(const float4*)(Wp + Hn);
    const float4 w2 = *(const float4*)(Wp + 2 * Hn);
    const float4 w3 = *(const float4*)(Wp + 3 * Hn);
#pragma unroll
    for (int r = 0; r < 8; r++) {
      const float4 x4 =
          *(const float4*)(X + ((size_t)(r0 + r) * Tn + t) * In + kx);
      fma4(acc[r], x4.x, w0);
      fma4(acc[r], x4.y, w1);
      fma4(acc[r], x4.z, w2);
      fma4(acc[r], x4.w, w3);
    }
  }
  reduce_vs(acc, c4, ksw, wv, part);
  __syncthreads();
  if (tid < 128) {
    const int r = tid >> 4, c = tid & 15;
    const float u =
        part[0][r][c] + part[1][r][c] + part[2][r][c] + part[3][r][c];
    const float av = alpha[0];
    v_out[(size_t)(r0 + r) * Hn + c0 + c] = av * hv - fmaxf(u + a1, 0.f);
  }
}

__global__ __launch_bounds__(256, 4) void k_phase2(
    float* __restrict__ h, const float* __restrict__ v_in,
    const float* __restrict__ WT, const float* __restrict__ alpha,
    const float* __restrict__ fc_w, float* __restrict__ out,
    float* __restrict__ hfin, int t, int last) {
  __shared__ float part[4][8][16];
  __shared__ float hn_s[8][16];
  const int ct = blockIdx.x & 63, rt = blockIdx.x >> 6;
  const int c0 = ct * 16, r0 = rt * 8;
  const int tid = threadIdx.x;
  const int c4 = tid & 3, kk = tid >> 2;
  const int col = c0 + 4 * c4;
  const int wv = tid >> 6, ksw = (tid & 63) >> 2;
  const float* vbase = v_in + (size_t)r0 * Hn;

  // DELTA vs R7: epilogue operands loaded early (h tile is only written by
  // THIS block after the sync; v_in read-only) — latency hides under GEMM.
  float hv = 0.f, vv = 0.f;
  if (tid < 128) {
    const int r = tid >> 4, c = tid & 15;
    hv = h[(size_t)(r0 + r) * Hn + c0 + c];
    vv = vbase[(size_t)r * Hn + c0 + c];
  }

  float4 acc[8];
#pragma unroll
  for (int r = 0; r < 8; r++) acc[r] = {0.f, 0.f, 0.f, 0.f};
  gemm8g(vbase, WT, kk, col, acc);
  reduce_vs(acc, c4, ksw, wv, part);
  __syncthreads();
  if (tid < 128) {
    const int r = tid >> 4, c = tid & 15;
    const float u =
        part[0][r][c] + part[1][r][c] + part[2][r][c] + part[3][r][c];
    const float av = alpha[0];
    const size_t hoff = (size_t)(r0 + r) * Hn + c0 + c;
    // phi = a*h - v; grad = a*v - (phi>0)*u; hn = h - LR*grad
    const float hn = hv - LR * (av * vv - ((av * hv - vv) > 0.f ? u : 0.f));
    h[hoff] = hn;
    if (last) hfin[hoff] = hn;
    hn_s[r][c] = hn;
  }
  __syncthreads();
  if (tid < 80) {  // FC partial over this block's 16 cols -> 80 atomics (R7)
    const int rr = tid / 10, c = tid % 10;
    float s = 0.f;
#pragma unroll
    for (int jj = 0; jj < 16; jj++)
      s += hn_s[rr][jj] * fc_w[(size_t)(c0 + jj) * Cn + c];
    atomicAdd(&out[((size_t)(r0 + rr) * Tn + t) * Cn + c], s);
  }
}

extern "C" void kernel_launch(void* const* d_in, const int* in_sizes, int n_in,
                              void* d_out, int out_size, void* d_ws, size_t ws_size,
                              hipStream_t stream) {
  const float* X      = (const float*)d_in[0];
  const float* hidden = (const float*)d_in[1];
  const float* alpha  = (const float*)d_in[2];
  const float* bias   = (const float*)d_in[3];
  const float* Wh     = (const float*)d_in[4];
  const float* Wx     = (const float*)d_in[5];
  const float* fc_w   = (const float*)d_in[6];
  const float* fc_b   = (const float*)d_in[7];
  float* out  = (float*)d_out;
  float* hfin = out + (size_t)Bsz * Tn * Cn;

  char* ws = (char*)d_ws;
  float* WhT   = (float*)ws;                        // 4 MB
  float* h_cur = WhT + (size_t)Hn * Hn;
  float* v_buf = h_cur + (size_t)Bsz * Hn;
  float* XW    = v_buf + (size_t)Bsz * Hn;          // 134 MB, [t][b][n]
  const size_t need =
      ((size_t)Hn * Hn + 2 * (size_t)Bsz * Hn + (size_t)Bsz * Tn * Hn) *
      sizeof(float);
  const bool pre = ws_size >= need;

  k_transpose<<<dim3(32, 32), 256, 0, stream>>>(Wh, WhT);
  k_init<<<(Bsz * Tn * Cn + 255) / 256, 256, 0, stream>>>(out, fc_b, h_cur,
                                                          hidden);
  if (pre) k_xw<<<8192, 256, 0, stream>>>(X, Wx, bias, XW);
  for (int t = 0; t < Tn; t++) {
    if (pre)
      k_phase1<1><<<1024, 256, 0, stream>>>(h_cur, X, Wh, Wx, bias, alpha, XW,
                                            v_buf, t);
    else
      k_phase1<0><<<1024, 256, 0, stream>>>(h_cur, X, Wh, Wx, bias, alpha, XW,
                                            v_buf, t);
    k_phase2<<<1024, 256, 0, stream>>>(h_cur, v_buf, WhT, alpha, fc_w, out,
                                       hfin, t, t == Tn - 1);
  }
}